// Round 1
// baseline (120.058 us; speedup 1.0000x reference)
//
#include <hip/hip_runtime.h>

// SAGEEncode: B=2048, F1=10, F2=25, D=128, H=256, N=261
// out[b] = [h0, mean_f h1] @ W2 + b2
//   h0    = relu([seeds, mean(hop1)] @ W1 + b1)
//   h1[f] = relu([hop1[f], mean_j hop2[f,j]] @ W1 + b1)

#define NB 2048
#define F1 10
#define F2 25
#define DD 128
#define HH 256
#define NN 261          // 1 + F1 + F1*F2
#define ITEMS 2         // batch items per block
#define THREADS 256

__global__ __launch_bounds__(THREADS)
void sage_fused(const float* __restrict__ x, const float* __restrict__ W1,
                const float* __restrict__ b1, const float* __restrict__ W2,
                const float* __restrict__ b2, float* __restrict__ out)
{
    // feat[it][0]   = [seeds | mean(hop1)]          (256 floats)
    // feat[it][1+f] = [hop1[f] | mean_j hop2[f,j]]  (256 floats)
    __shared__ float feat[ITEMS][11][2 * DD];
    __shared__ float feat2[ITEMS][2 * HH];

    const int t = threadIdx.x;
    const int blk = blockIdx.x;

    // ---- Phase 1a: seeds + hop1 rows -> feat[it][r][0:128] (float4 coalesced)
    for (int it = 0; it < ITEMS; ++it) {
        const float4* xb = reinterpret_cast<const float4*>(x)
                         + (size_t)(blk * ITEMS + it) * (NN * DD / 4);
        for (int idx = t; idx < 11 * 32; idx += THREADS) {
            int r = idx >> 5, d4 = idx & 31;
            reinterpret_cast<float4*>(&feat[it][r][0])[d4] = xb[idx];
        }
    }
    __syncthreads();

    // ---- Phase 1b: m1 = mean(hop1) -> feat[it][0][128+d]
    {
        int it = t >> 7, d = t & 127;
        float s = 0.f;
        #pragma unroll
        for (int f = 0; f < F1; ++f) s += feat[it][1 + f][d];
        feat[it][0][DD + d] = s * (1.f / F1);
    }

    // ---- Phase 1c: hop2 means -> feat[it][1+f][128..255]
    // thread t: it = t>>7, d4 = (t&127)&31, fg = (t&127)>>5; each (f,d4) owned
    // by exactly one thread -> no cross-thread reduce, no barriers in f-loop.
    {
        int it = t >> 7;
        int rem = t & 127;
        int d4 = rem & 31;
        int fg = rem >> 5;   // 0..3
        const float4* xb = reinterpret_cast<const float4*>(x)
                         + (size_t)(blk * ITEMS + it) * (NN * DD / 4);
        for (int f = fg; f < F1; f += 4) {
            const float4* row = xb + (size_t)(1 + F1 + f * F2) * (DD / 4) + d4;
            float4 acc = make_float4(0.f, 0.f, 0.f, 0.f);
            #pragma unroll
            for (int j = 0; j < F2; ++j) {
                float4 v = row[j * (DD / 4)];
                acc.x += v.x; acc.y += v.y; acc.z += v.z; acc.w += v.w;
            }
            const float inv = 1.f / F2;
            acc.x *= inv; acc.y *= inv; acc.z *= inv; acc.w *= inv;
            reinterpret_cast<float4*>(&feat[it][1 + f][DD])[d4] = acc;
        }
    }
    __syncthreads();

    // ---- Phase 2: h rows = relu(feat @ W1 + b1); thread t owns column c = t
    const int c = t;
    float acc[ITEMS][11];
    #pragma unroll
    for (int it = 0; it < ITEMS; ++it)
        #pragma unroll
        for (int r = 0; r < 11; ++r) acc[it][r] = 0.f;

    #pragma unroll 2
    for (int k4 = 0; k4 < (2 * DD) / 4; ++k4) {   // 64 iterations over K=256
        // W1[k][c]: consecutive lanes -> consecutive addresses (coalesced, L2-hot)
        float w0 = W1[(k4 * 4 + 0) * HH + c];
        float w1 = W1[(k4 * 4 + 1) * HH + c];
        float w2 = W1[(k4 * 4 + 2) * HH + c];
        float w3 = W1[(k4 * 4 + 3) * HH + c];
        #pragma unroll
        for (int it = 0; it < ITEMS; ++it) {
            #pragma unroll
            for (int r = 0; r < 11; ++r) {
                float4 fv = reinterpret_cast<const float4*>(&feat[it][r][0])[k4];
                acc[it][r] = fmaf(fv.x, w0, acc[it][r]);
                acc[it][r] = fmaf(fv.y, w1, acc[it][r]);
                acc[it][r] = fmaf(fv.z, w2, acc[it][r]);
                acc[it][r] = fmaf(fv.w, w3, acc[it][r]);
            }
        }
    }
    {
        float bb1 = b1[c];
        #pragma unroll
        for (int it = 0; it < ITEMS; ++it) {
            float h0 = fmaxf(acc[it][0] + bb1, 0.f);
            float hs = 0.f;
            #pragma unroll
            for (int r = 1; r < 11; ++r) hs += fmaxf(acc[it][r] + bb1, 0.f);
            feat2[it][c] = h0;            // [h0 | mean_f h1]
            feat2[it][HH + c] = hs * (1.f / F1);
        }
    }
    __syncthreads();

    // ---- Phase 3: out = feat2 @ W2 + b2
    float acco[ITEMS];
    #pragma unroll
    for (int it = 0; it < ITEMS; ++it) acco[it] = 0.f;

    #pragma unroll 2
    for (int k4 = 0; k4 < (2 * HH) / 4; ++k4) {   // 128 iterations over K=512
        float w0 = W2[(k4 * 4 + 0) * HH + c];
        float w1 = W2[(k4 * 4 + 1) * HH + c];
        float w2 = W2[(k4 * 4 + 2) * HH + c];
        float w3 = W2[(k4 * 4 + 3) * HH + c];
        #pragma unroll
        for (int it = 0; it < ITEMS; ++it) {
            float4 fv = reinterpret_cast<const float4*>(&feat2[it][0])[k4];
            acco[it] = fmaf(fv.x, w0, acco[it]);
            acco[it] = fmaf(fv.y, w1, acco[it]);
            acco[it] = fmaf(fv.z, w2, acco[it]);
            acco[it] = fmaf(fv.w, w3, acco[it]);
        }
    }
    {
        float bb2 = b2[c];
        #pragma unroll
        for (int it = 0; it < ITEMS; ++it)
            out[(size_t)(blk * ITEMS + it) * HH + c] = acco[it] + bb2;
    }
}

extern "C" void kernel_launch(void* const* d_in, const int* in_sizes, int n_in,
                              void* d_out, int out_size, void* d_ws, size_t ws_size,
                              hipStream_t stream) {
    const float* x  = (const float*)d_in[0];
    const float* W1 = (const float*)d_in[1];
    const float* b1 = (const float*)d_in[2];
    const float* W2 = (const float*)d_in[3];
    const float* b2 = (const float*)d_in[4];
    float* out = (float*)d_out;

    dim3 grid(NB / ITEMS);
    sage_fused<<<grid, dim3(THREADS), 0, stream>>>(x, W1, b1, W2, b2, out);
}

// Round 2
// 112.431 us; speedup vs baseline: 1.0678x; 1.0678x over previous
//
#include <hip/hip_runtime.h>

// SAGEEncode: B=2048, F1=10, F2=25, D=128, H=256, N=261
// Two-kernel pipeline:
//   K1 sage_prep: stream x -> feat[b][16][256] bf16 (row0=[seeds|mean hop1],
//                 rows 1..10=[hop1[f]|mean_j hop2[f,j]], rows 11..15 = 0),
//                 plus W1->W1t, W2->W2t bf16 N-major transposes (2 extra blocks).
//   K2 sage_gemm: per block 8 items: GEMM1 (M=128,K=256,N=256) via
//                 mfma_f32_16x16x32_bf16 with A/B frags straight from global
//                 (K-major, 16B/lane), relu+bias, in-register h0/mean via
//                 shfl_xor, feat2 in LDS (16.6KB), GEMM2 (K=512) -> out.

#define NB 2048
#define F1 10
#define F2 25
#define DD 128
#define HH 256
#define NN 261

typedef __attribute__((ext_vector_type(8))) short short8;   // 8 bf16 (4 VGPR)
typedef __attribute__((ext_vector_type(4))) float f32x4;    // MFMA acc

__device__ __forceinline__ ushort f2bf(float f) {           // RNE, finite inputs
    unsigned u = __builtin_bit_cast(unsigned, f);
    u = (u + 0x7FFFu + ((u >> 16) & 1u)) >> 16;
    return (ushort)u;
}
__device__ __forceinline__ float bf2f(ushort h) {
    unsigned u = ((unsigned)h) << 16;
    return __builtin_bit_cast(float, u);
}

// ---------------- K1: streaming prep ----------------
__global__ __launch_bounds__(320)
void sage_prep(const float* __restrict__ x, const float* __restrict__ W1,
               const float* __restrict__ W2, ushort* __restrict__ feat,
               ushort* __restrict__ W1t, ushort* __restrict__ W2t)
{
    const int b = blockIdx.x;
    const int t = threadIdx.x;

    if (b >= NB) {                       // weight transpose/convert blocks
        if (t < HH) {
            const int c = t;
            if (b == NB) {               // W1 [256][256] -> W1t[c][k]
                for (int k = 0; k < 2 * DD; ++k)
                    W1t[c * (2 * DD) + k] = f2bf(W1[k * HH + c]);
            } else {                     // W2 [512][256] -> W2t[c][k]
                for (int k = 0; k < 2 * HH; ++k)
                    W2t[c * (2 * HH) + k] = f2bf(W2[k * HH + c]);
            }
        }
        return;
    }

    __shared__ float4 hsum[F1][32];
    const int f = t >> 5, d4 = t & 31;   // f: 0..9, d4: 0..31 (float4 cols)
    const float4* xb = reinterpret_cast<const float4*>(x) + (size_t)b * (NN * DD / 4);

    // hop1 row f (coalesced: wave = two rows of 512B)
    float4 h1 = xb[(1 + f) * 32 + d4];

    // hop2 mean over j for (f, d4)
    float4 s = make_float4(0.f, 0.f, 0.f, 0.f);
    const float4* h2 = xb + (1 + F1 + f * F2) * 32 + d4;
    #pragma unroll 5
    for (int j = 0; j < F2; ++j) {
        float4 v = h2[j * 32];
        s.x += v.x; s.y += v.y; s.z += v.z; s.w += v.w;
    }
    const float invF2 = 1.f / F2;
    s.x *= invF2; s.y *= invF2; s.z *= invF2; s.w *= invF2;

    // feat row 1+f = [hop1[f] | mean hop2[f]]
    ushort* fr = feat + ((size_t)b * 16 + 1 + f) * (2 * DD);
    ushort4 lo = { f2bf(h1.x), f2bf(h1.y), f2bf(h1.z), f2bf(h1.w) };
    ushort4 hi = { f2bf(s.x),  f2bf(s.y),  f2bf(s.z),  f2bf(s.w)  };
    *reinterpret_cast<ushort4*>(fr + d4 * 4)      = lo;
    *reinterpret_cast<ushort4*>(fr + DD + d4 * 4) = hi;

    hsum[f][d4] = h1;
    __syncthreads();

    ushort* r0 = feat + (size_t)b * 16 * (2 * DD);
    if (f == 0) {                        // mean(hop1) -> row0 high half
        float4 a = make_float4(0.f, 0.f, 0.f, 0.f);
        #pragma unroll
        for (int ff = 0; ff < F1; ++ff) {
            float4 v = hsum[ff][d4];
            a.x += v.x; a.y += v.y; a.z += v.z; a.w += v.w;
        }
        const float invF1 = 1.f / F1;
        ushort4 m = { f2bf(a.x * invF1), f2bf(a.y * invF1),
                      f2bf(a.z * invF1), f2bf(a.w * invF1) };
        *reinterpret_cast<ushort4*>(r0 + DD + d4 * 4) = m;
    } else if (f == 1) {                 // seeds -> row0 low half
        float4 sv = xb[d4];
        ushort4 v = { f2bf(sv.x), f2bf(sv.y), f2bf(sv.z), f2bf(sv.w) };
        *reinterpret_cast<ushort4*>(r0 + d4 * 4) = v;
    } else if (f >= 2 && f < 7) {        // zero pad rows 11..15
        const int row = 9 + f;
        ushort* zr = feat + ((size_t)b * 16 + row) * (2 * DD);
        ushort4 z = { 0, 0, 0, 0 };
        *reinterpret_cast<ushort4*>(zr + d4 * 4)      = z;
        *reinterpret_cast<ushort4*>(zr + DD + d4 * 4) = z;
    }
}

// ---------------- K2: MFMA GEMMs ----------------
__global__ __launch_bounds__(512)
void sage_gemm(const ushort* __restrict__ feat, const ushort* __restrict__ W1t,
               const ushort* __restrict__ W2t, const float* __restrict__ b1,
               const float* __restrict__ b2, float* __restrict__ out)
{
    __shared__ ushort f2lds[16][520];    // feat2: 8 items (pad 16) x K=512, +8 pad

    const int t  = threadIdx.x;
    const int w  = t >> 6, l = t & 63;
    const int lr = l & 15, lg = l >> 4;  // lane row/col-in-tile, k-group
    const int wm = w >> 2, wn = w & 3;   // wave grid 2(M) x 4(N)
    const int item0 = blockIdx.x * 8;

    // ---- GEMM1: C = feat(128x256) @ W1 (256x256), A/B frags from global ----
    f32x4 acc[4][4];
    #pragma unroll
    for (int mt = 0; mt < 4; ++mt)
        #pragma unroll
        for (int nt = 0; nt < 4; ++nt)
            acc[mt][nt] = (f32x4){0.f, 0.f, 0.f, 0.f};

    #pragma unroll 2
    for (int kt = 0; kt < 8; ++kt) {
        short8 af[4], bfr[4];
        #pragma unroll
        for (int mt = 0; mt < 4; ++mt) {
            size_t row = (size_t)item0 * 16 + wm * 64 + mt * 16 + lr;
            af[mt] = *reinterpret_cast<const short8*>(feat + row * 256 + kt * 32 + lg * 8);
        }
        #pragma unroll
        for (int nt = 0; nt < 4; ++nt) {
            int col = wn * 64 + nt * 16 + lr;
            bfr[nt] = *reinterpret_cast<const short8*>(W1t + (size_t)col * 256 + kt * 32 + lg * 8);
        }
        #pragma unroll
        for (int mt = 0; mt < 4; ++mt)
            #pragma unroll
            for (int nt = 0; nt < 4; ++nt)
                acc[mt][nt] = __builtin_amdgcn_mfma_f32_16x16x32_bf16(
                    af[mt], bfr[nt], acc[mt][nt], 0, 0, 0);
    }

    // ---- epilogue: relu+bias; h0 & mean(h1 rows 1..10) in-register ----
    // C/D layout (m89-verified): col = lane&15, row = (lane>>4)*4 + reg.
    // One mtile == one item (16 rows).
    if (t < 256) {                       // zero f2 pad rows 8..15 meanwhile
        const int rr = 8 + (t >> 5), cc = (t & 31) * 16;
        ushort4 z = {0, 0, 0, 0};
        #pragma unroll
        for (int q = 0; q < 4; ++q)
            *reinterpret_cast<ushort4*>(&f2lds[rr][cc + q * 4]) = z;
    }
    #pragma unroll
    for (int nt = 0; nt < 4; ++nt) {
        const int col = wn * 64 + nt * 16 + lr;
        const float bb = b1[col];
        #pragma unroll
        for (int mt = 0; mt < 4; ++mt) {
            const int item = wm * 4 + mt;
            float rv0 = fmaxf(acc[mt][nt][0] + bb, 0.f);
            float rv1 = fmaxf(acc[mt][nt][1] + bb, 0.f);
            float rv2 = fmaxf(acc[mt][nt][2] + bb, 0.f);
            float rv3 = fmaxf(acc[mt][nt][3] + bb, 0.f);
            // partial sum over rows 1..10 (row = lg*4 + r)
            float p = 0.f;
            p += (lg * 4 + 0 >= 1 && lg * 4 + 0 <= 10) ? rv0 : 0.f;
            p += (lg * 4 + 1 >= 1 && lg * 4 + 1 <= 10) ? rv1 : 0.f;
            p += (lg * 4 + 2 >= 1 && lg * 4 + 2 <= 10) ? rv2 : 0.f;
            p += (lg * 4 + 3 >= 1 && lg * 4 + 3 <= 10) ? rv3 : 0.f;
            p += __shfl_xor(p, 16, 64);
            p += __shfl_xor(p, 32, 64);
            if (lg == 0) {               // lane holds h0 (row 0) in rv0
                f2lds[item][col]       = f2bf(rv0);
                f2lds[item][256 + col] = f2bf(p * (1.f / F1));
            }
        }
    }
    __syncthreads();

    // ---- GEMM2: out(8x256) = feat2(8x512) @ W2(512x256) ----
    f32x4 acc2[2];
    acc2[0] = (f32x4){0.f, 0.f, 0.f, 0.f};
    acc2[1] = (f32x4){0.f, 0.f, 0.f, 0.f};
    #pragma unroll 2
    for (int kt = 0; kt < 16; ++kt) {
        short8 a2 = *reinterpret_cast<const short8*>(&f2lds[lr][kt * 32 + lg * 8]);
        #pragma unroll
        for (int q = 0; q < 2; ++q) {
            const int col = (w * 2 + q) * 16 + lr;
            short8 b2f = *reinterpret_cast<const short8*>(W2t + (size_t)col * 512 + kt * 32 + lg * 8);
            acc2[q] = __builtin_amdgcn_mfma_f32_16x16x32_bf16(a2, b2f, acc2[q], 0, 0, 0);
        }
    }
    #pragma unroll
    for (int q = 0; q < 2; ++q) {
        const int col = (w * 2 + q) * 16 + lr;
        const float bb = b2[col];
        #pragma unroll
        for (int r = 0; r < 4; ++r) {
            const int row = lg * 4 + r;  // row == item index (0..7 valid)
            if (row < 8)
                out[(size_t)(item0 + row) * HH + col] = acc2[q][r] + bb;
        }
    }
}

extern "C" void kernel_launch(void* const* d_in, const int* in_sizes, int n_in,
                              void* d_out, int out_size, void* d_ws, size_t ws_size,
                              hipStream_t stream) {
    const float* x  = (const float*)d_in[0];
    const float* W1 = (const float*)d_in[1];
    const float* b1 = (const float*)d_in[2];
    const float* W2 = (const float*)d_in[3];
    const float* b2 = (const float*)d_in[4];
    float* out = (float*)d_out;

    ushort* feat = (ushort*)d_ws;                         // 2048*16*256 bf16 = 16.78 MB
    ushort* W1t  = feat + (size_t)NB * 16 * 256;          // 256*256 bf16
    ushort* W2t  = W1t + 256 * 256;                       // 256*512 bf16

    sage_prep<<<dim3(NB + 2), dim3(320), 0, stream>>>(x, W1, W2, feat, W1t, W2t);
    sage_gemm<<<dim3(NB / 8), dim3(512), 0, stream>>>(feat, W1t, W2t, b1, b2, out);
}

// Round 3
// 75.601 us; speedup vs baseline: 1.5880x; 1.4871x over previous
//
#include <hip/hip_runtime.h>

// SAGEEncode fused: B=2048, F1=10, F2=25, D=128, H=256, N=261
// K0 prep_weights: W1(256x256),W2(512x256) f32 -> W1t[256][256],W2t[256][512] bf16
//                  (N-major, K-contiguous) via LDS tile transpose. 24 blocks.
// K1 sage_fused:   4 items/block. Stream x -> feat LDS (bf16, 16 rows/item,
//                  XOR-swizzled), GEMM1 mfma_16x16x32_bf16, relu+bias, h0/mean
//                  via shfl_xor, feat2 LDS, GEMM2 -> out. 512 blocks x 256 thr.

#define NB 2048
#define F1 10
#define F2 25
#define DD 128
#define HH 256
#define NN 261
#define ITEMS 4
#define THREADS 256

typedef __attribute__((ext_vector_type(8))) short short8;   // 8 bf16
typedef __attribute__((ext_vector_type(4))) float f32x4;    // MFMA acc

__device__ __forceinline__ ushort f2bf(float f) {           // RNE, finite
    unsigned u = __builtin_bit_cast(unsigned, f);
    u = (u + 0x7FFFu + ((u >> 16) & 1u)) >> 16;
    return (ushort)u;
}
__device__ __forceinline__ float bf2f(ushort h) {
    unsigned u = ((unsigned)h) << 16;
    return __builtin_bit_cast(float, u);
}
// XOR-swizzle on ushort index (byte bits 4..6): spreads 16 rows x 4 kgroups
// of a ds_read_b128 A-fragment evenly over banks (8 dwords/bank = minimum).
__device__ __forceinline__ int swz(int uidx, int row) {
    return uidx ^ ((row & 7) << 3);
}

// ---------------- K0: weight transpose+convert ----------------
__global__ __launch_bounds__(256)
void prep_weights(const float* __restrict__ W1, const float* __restrict__ W2,
                  ushort* __restrict__ W1t, ushort* __restrict__ W2t)
{
    __shared__ float tile[32][257];
    const int b = blockIdx.x, t = threadIdx.x;
    const float* src; ushort* dst; int K, c0, k0;
    if (b < 8) { src = W1; dst = W1t; K = 2 * DD; c0 = b * 32; k0 = 0; }
    else { int bb = b - 8; src = W2; dst = W2t; K = 2 * HH;
           c0 = (bb & 7) * 32; k0 = (bb >> 3) * 256; }

    // load 32c x 256k tile, coalesced along c
    #pragma unroll 4
    for (int kr = 0; kr < 32; ++kr) {
        int kl = kr * 8 + (t >> 5);
        tile[t & 31][kl] = src[(size_t)(k0 + kl) * HH + c0 + (t & 31)];
    }
    __syncthreads();
    // write K-contiguous bf16, 16B/lane
    const int cl = t >> 3;
    #pragma unroll
    for (int p = 0; p < 4; ++p) {
        int kc = (t & 7) + p * 8;
        short8 v;
        #pragma unroll
        for (int i = 0; i < 8; ++i) v[i] = (short)f2bf(tile[cl][kc * 8 + i]);
        *reinterpret_cast<short8*>(dst + (size_t)(c0 + cl) * K + k0 + kc * 8) = v;
    }
}

// ---------------- K1: fused stream + MFMA ----------------
__global__ __launch_bounds__(THREADS)
void sage_fused(const float* __restrict__ x, const ushort* __restrict__ W1t,
                const ushort* __restrict__ W2t, const float* __restrict__ b1,
                const float* __restrict__ b2, float* __restrict__ out)
{
    __shared__ ushort featL[ITEMS * 16 * 256];   // 32 KB, swizzled rows
    __shared__ ushort f2lds[16][520];            // 16.6 KB feat2 (rows>=ITEMS zero)

    const int t = threadIdx.x;
    const int item0 = blockIdx.x * ITEMS;
    const size_t base = (size_t)item0 * (NN * DD);

    // ---- Phase 1: stream x -> feat rows 1..10 = [hop1[f] | mean_j hop2[f,j]]
    {
        const int g = t >> 5, d4 = t & 31;
        #pragma unroll
        for (int p = 0; p < 5; ++p) {
            int pi = g + p * 8;                  // 0..39 = item*10 + f
            int item = pi / 10, f = pi % 10;
            const float4* xb = reinterpret_cast<const float4*>(x + base + (size_t)item * (NN * DD));
            float4 h1 = xb[(1 + f) * 32 + d4];
            float4 s = make_float4(0.f, 0.f, 0.f, 0.f);
            const float4* h2 = xb + (1 + F1 + f * F2) * 32 + d4;
            #pragma unroll 5
            for (int j = 0; j < F2; ++j) {
                float4 v = h2[j * 32];
                s.x += v.x; s.y += v.y; s.z += v.z; s.w += v.w;
            }
            const float invF2 = 1.f / F2;
            int row = 1 + f;
            int ub = (item * 16 + row) * 256;
            ushort4 lo = { f2bf(h1.x), f2bf(h1.y), f2bf(h1.z), f2bf(h1.w) };
            ushort4 hi = { f2bf(s.x * invF2), f2bf(s.y * invF2),
                           f2bf(s.z * invF2), f2bf(s.w * invF2) };
            *reinterpret_cast<ushort4*>(&featL[swz(ub + d4 * 4, row)]) = lo;
            *reinterpret_cast<ushort4*>(&featL[swz(ub + DD + d4 * 4, row)]) = hi;
        }
    }
    __syncthreads();

    // ---- Phase 1b: row0 = [seeds | mean(hop1 rows, from LDS bf16)] + zero pad
    #pragma unroll
    for (int q = 0; q < 2; ++q) {
        int idx = t + q * 256;                   // 0..511
        int item = idx >> 7, d = idx & 127;
        int r0 = item * 16 * 256;
        float sv = x[base + (size_t)item * (NN * DD) + d];
        featL[swz(r0 + d, 0)] = f2bf(sv);
        float m = 0.f;
        #pragma unroll
        for (int f = 1; f <= F1; ++f) m += bf2f(featL[swz(r0 + f * 256 + d, f)]);
        featL[swz(r0 + DD + d, 0)] = f2bf(m * (1.f / F1));
    }
    {
        short8 zz = { 0, 0, 0, 0, 0, 0, 0, 0 };
        for (int z = t; z < ITEMS * 5 * 32; z += THREADS) {   // rows 11..15
            int item = z / 160, rem = z % 160;
            int row = 11 + rem / 32, kc = rem % 32;
            *reinterpret_cast<short8*>(&featL[swz((item * 16 + row) * 256 + kc * 8, row)]) = zz;
        }
        for (int z = t; z < 12 * 64; z += THREADS) {          // f2 rows 4..15
            int row = ITEMS + (z >> 6), kc = z & 63;
            *reinterpret_cast<short8*>(&f2lds[row][kc * 8]) = zz;
        }
    }
    __syncthreads();

    // ---- GEMM1: h(64x256) = relu(feat(64x256) @ W1 + b1), per-item 16-row Mtiles
    const int w = t >> 6, l = t & 63;
    const int lr = l & 15, lg = l >> 4;
    f32x4 acc[ITEMS][4];
    #pragma unroll
    for (int it = 0; it < ITEMS; ++it)
        #pragma unroll
        for (int i = 0; i < 4; ++i) acc[it][i] = (f32x4){0.f, 0.f, 0.f, 0.f};

    #pragma unroll 2
    for (int kt = 0; kt < 8; ++kt) {
        short8 af[ITEMS], bf[4];
        #pragma unroll
        for (int it = 0; it < ITEMS; ++it)
            af[it] = *reinterpret_cast<const short8*>(
                &featL[swz((it * 16 + lr) * 256 + kt * 32 + lg * 8, lr)]);
        #pragma unroll
        for (int i = 0; i < 4; ++i) {
            int col = (w * 4 + i) * 16 + lr;
            bf[i] = *reinterpret_cast<const short8*>(W1t + (size_t)col * 256 + kt * 32 + lg * 8);
        }
        #pragma unroll
        for (int it = 0; it < ITEMS; ++it)
            #pragma unroll
            for (int i = 0; i < 4; ++i)
                acc[it][i] = __builtin_amdgcn_mfma_f32_16x16x32_bf16(af[it], bf[i], acc[it][i], 0, 0, 0);
    }

    // ---- epilogue: C/D row = lg*4+reg, col = lr (m89 layout). h0 + mean(h1)
    #pragma unroll
    for (int i = 0; i < 4; ++i) {
        const int col = (w * 4 + i) * 16 + lr;
        const float bb = b1[col];
        #pragma unroll
        for (int it = 0; it < ITEMS; ++it) {
            f32x4 a = acc[it][i];
            float r0v = fmaxf(a[0] + bb, 0.f);
            float r1v = fmaxf(a[1] + bb, 0.f);
            float r2v = fmaxf(a[2] + bb, 0.f);
            float r3v = fmaxf(a[3] + bb, 0.f);
            const int rb = lg * 4;
            float p = 0.f;
            p += (rb + 0 >= 1 && rb + 0 <= 10) ? r0v : 0.f;
            p += (rb + 1 >= 1 && rb + 1 <= 10) ? r1v : 0.f;
            p += (rb + 2 >= 1 && rb + 2 <= 10) ? r2v : 0.f;
            p += (rb + 3 >= 1 && rb + 3 <= 10) ? r3v : 0.f;
            p += __shfl_xor(p, 16, 64);
            p += __shfl_xor(p, 32, 64);
            if (lg == 0) {
                f2lds[it][col]       = f2bf(r0v);
                f2lds[it][256 + col] = f2bf(p * (1.f / F1));
            }
        }
    }
    __syncthreads();

    // ---- GEMM2: out(4x256) = feat2(4x512) @ W2 + b2
    f32x4 acc2[4];
    #pragma unroll
    for (int i = 0; i < 4; ++i) acc2[i] = (f32x4){0.f, 0.f, 0.f, 0.f};
    #pragma unroll 2
    for (int kt = 0; kt < 16; ++kt) {
        short8 a2 = *reinterpret_cast<const short8*>(&f2lds[lr][kt * 32 + lg * 8]);
        #pragma unroll
        for (int i = 0; i < 4; ++i) {
            int col = (w * 4 + i) * 16 + lr;
            short8 bv = *reinterpret_cast<const short8*>(W2t + (size_t)col * 512 + kt * 32 + lg * 8);
            acc2[i] = __builtin_amdgcn_mfma_f32_16x16x32_bf16(a2, bv, acc2[i], 0, 0, 0);
        }
    }
    #pragma unroll
    for (int i = 0; i < 4; ++i) {
        const int col = (w * 4 + i) * 16 + lr;
        const float bb = b2[col];
        #pragma unroll
        for (int r = 0; r < 4; ++r) {
            const int row = lg * 4 + r;
            if (row < ITEMS)
                out[(size_t)(item0 + row) * HH + col] = acc2[i][r] + bb;
        }
    }
}

extern "C" void kernel_launch(void* const* d_in, const int* in_sizes, int n_in,
                              void* d_out, int out_size, void* d_ws, size_t ws_size,
                              hipStream_t stream) {
    const float* x  = (const float*)d_in[0];
    const float* W1 = (const float*)d_in[1];
    const float* b1 = (const float*)d_in[2];
    const float* W2 = (const float*)d_in[3];
    const float* b2 = (const float*)d_in[4];
    float* out = (float*)d_out;

    ushort* W1t = (ushort*)d_ws;                 // 256*256 bf16 = 128 KB
    ushort* W2t = W1t + 256 * 256;               // 256*512 bf16 = 256 KB

    prep_weights<<<dim3(24), dim3(256), 0, stream>>>(W1, W2, W1t, W2t);
    sage_fused<<<dim3(NB / ITEMS), dim3(THREADS), 0, stream>>>(x, W1t, W2t, b1, b2, out);
}